// Round 1
// baseline (13599.260 us; speedup 1.0000x reference)
//
#include <hip/hip_runtime.h>
#include <hip/hip_bf16.h>
#include <math.h>

#define D_    1024
#define DFF_  4096
#define LT_   2
#define HT_   16
#define C_    4
#define DC_   256
#define DFFC_ 1024
#define LC_   4
#define HC_   4
#define B_    2
#define T_    1024
#define VSZ_  32000

__device__ __forceinline__ float gelu_f(float x) {
  // jax.nn.gelu default (approximate=True, tanh form)
  const float c = 0.7978845608028654f;
  return 0.5f * x * (1.f + tanhf(c * (x + 0.044715f * x * x * x)));
}

// ---------------- embedding gather: x[b,t,:] = tok_emb[ids[b,t],:] ----------------
__global__ void embed_k(const int* __restrict__ ids, const float* __restrict__ emb,
                        float* __restrict__ X) {
  int bt = blockIdx.x;
  int id = ids[bt];
  const float* e = emb + (long)id * D_;
  float* x = X + (long)bt * D_;
  for (int i = threadIdx.x; i < D_; i += 256) x[i] = e[i];
}

// ---------------- rmsnorm: one block per row ----------------
// weight selected per row-group: wp = W + (row/rowsPerGroup)*wStride
__global__ __launch_bounds__(256) void rmsnorm_k(const float* __restrict__ Xi,
    float* __restrict__ Y, const float* __restrict__ W, int Dn,
    int rowsPerGroup, long wStride)
{
  int r = blockIdx.x;
  const float* xp = Xi + (long)r * Dn;
  float* yp = Y + (long)r * Dn;
  const float* wp = W + (long)(r / rowsPerGroup) * wStride;
  __shared__ float red[256];
  float s = 0.f;
  for (int i = threadIdx.x; i < Dn; i += 256) { float v = xp[i]; s += v * v; }
  red[threadIdx.x] = s;
  __syncthreads();
  for (int w = 128; w; w >>= 1) {
    if (threadIdx.x < w) red[threadIdx.x] += red[threadIdx.x + w];
    __syncthreads();
  }
  float scale = 1.f / sqrtf(red[0] / (float)Dn + 1e-6f);
  for (int i = threadIdx.x; i < Dn; i += 256)
    yp[i] = xp[i] * scale * wp[i];
}

// ---------------- RoPE in-place on (NB, T, nh, 64); one thread per (row, pair) ----------------
__global__ void rope_k(float* __restrict__ Xq, long total, int T, int nh) {
  long idx = (long)blockIdx.x * 256 + threadIdx.x;
  if (idx >= total) return;
  int i = (int)(idx & 31);
  long rest = idx >> 5;
  int h = (int)(rest % nh);
  rest /= nh;                     // = nb*T + t
  int t = (int)(rest % T);
  float inv = powf(10000.f, -(float)(2 * i) / 64.f);
  float f = (float)t * inv;
  float c = cosf(f), s = sinf(f);
  float* p = Xq + (rest * (long)nh + h) * 64;
  float x1 = p[i], x2 = p[i + 32];
  p[i]      = x1 * c - x2 * s;
  p[i + 32] = x2 * c + x1 * s;
}

// ---------------- causal attention, online softmax; one block per (b,h,q) row ----------------
// Q/K/V/O layout: (NB, T, nh, 64)
// Wave-shuffle reductions (3 barriers/chunk) + PV parallelized over 4 j-groups.
__global__ __launch_bounds__(256) void attn_k(const float* __restrict__ Q,
    const float* __restrict__ Kt, const float* __restrict__ Vt,
    float* __restrict__ O, int T, int nh, float scale)
{
  int qi = blockIdx.x, h = blockIdx.y;
  long b = blockIdx.z;
  int tid = threadIdx.x;
  int lane = tid & 63, wv = tid >> 6;
  long rs = (long)nh * 64;
  const float* qp = Q + (b * T + qi) * rs + h * 64;
  __shared__ float qv[64], ov[64], pr[256], part[256], red4[4], sum4[4];
  if (tid < 64) { qv[tid] = qp[tid]; ov[tid] = 0.f; }
  __syncthreads();
  float m = -1e30f, l = 0.f;
  for (int k0 = 0; k0 <= qi; k0 += 256) {
    int jn = min(256, qi + 1 - k0);
    float s = -1e30f;
    if (tid < jn) {
      const float* kp = Kt + (b * T + k0 + tid) * rs + h * 64;
      float acc = 0.f;
#pragma unroll
      for (int d = 0; d < 64; d++) acc += qv[d] * kp[d];
      s = acc * scale;
    }
    // chunk max: wave shuffle + 4-way cross-wave combine
    float wm = s;
#pragma unroll
    for (int off = 32; off; off >>= 1) wm = fmaxf(wm, __shfl_xor(wm, off));
    if (lane == 0) red4[wv] = wm;
    __syncthreads();                               // A
    float nm = fmaxf(m, fmaxf(fmaxf(red4[0], red4[1]), fmaxf(red4[2], red4[3])));
    float p = (tid < jn) ? expf(s - nm) : 0.f;
    pr[tid] = p;
    float ws = p;
#pragma unroll
    for (int off = 32; off; off >>= 1) ws += __shfl_xor(ws, off);
    if (lane == 0) sum4[wv] = ws;
    __syncthreads();                               // B
    float csum = sum4[0] + sum4[1] + sum4[2] + sum4[3];
    float alpha = expf(m - nm);   // first chunk: exp(-huge) == 0, harmless
    l = l * alpha + csum;
    // PV: 4 j-groups of 64 lanes each, coalesced per j
    {
      int d = tid & 63, jg = tid >> 6;
      const float* vb = Vt + (b * T + k0) * rs + h * 64 + d;
      float acc = 0.f;
      for (int j = jg; j < jn; j += 4) acc += pr[j] * vb[(long)j * rs];
      part[tid] = acc;
    }
    __syncthreads();                               // C
    if (tid < 64)
      ov[tid] = ov[tid] * alpha + part[tid] + part[tid + 64] + part[tid + 128] + part[tid + 192];
    m = nm;
  }
  __syncthreads();
  if (tid < 64) O[(b * T + qi) * rs + h * 64 + tid] = ov[tid] / l;
}

// ---------------- cross-column merge attention: one wave per (b,t,h), softmax over 4 columns ----------------
// Q/K/V/O layout: (C, B, T, HC, 64)
__global__ __launch_bounds__(64) void merge_attn_k(const float* __restrict__ Q,
    const float* __restrict__ Kt, const float* __restrict__ Vt,
    float* __restrict__ O, float scale)
{
  int bid = blockIdx.x;              // ((b*T + t)*HC + h)
  int h = bid & (HC_ - 1);
  int t = (bid >> 2) & (T_ - 1);
  int b = bid >> 12;
  int d = threadIdx.x;
  long base[C_];
  float q[C_], k[C_], v[C_];
#pragma unroll
  for (int c = 0; c < C_; c++) {
    base[c] = ((((long)c * B_ + b) * T_ + t) * HC_ + h) * 64 + d;
    q[c] = Q[base[c]]; k[c] = Kt[base[c]]; v[c] = Vt[base[c]];
  }
  float s[C_][C_];
#pragma unroll
  for (int i = 0; i < C_; i++)
#pragma unroll
    for (int j = 0; j < C_; j++) {
      float p = q[i] * k[j];
#pragma unroll
      for (int off = 32; off; off >>= 1) p += __shfl_xor(p, off);
      s[i][j] = p * scale;
    }
#pragma unroll
  for (int i = 0; i < C_; i++) {
    float mx = fmaxf(fmaxf(s[i][0], s[i][1]), fmaxf(s[i][2], s[i][3]));
    float e0 = expf(s[i][0] - mx), e1 = expf(s[i][1] - mx),
          e2 = expf(s[i][2] - mx), e3 = expf(s[i][3] - mx);
    float inv = 1.f / (e0 + e1 + e2 + e3);
    O[base[i]] = (e0 * v[0] + e1 * v[1] + e2 * v[2] + e3 * v[3]) * inv;
  }
}

// ---------------- transpose (C,B,T,DC) -> (B,T,C*DC) ----------------
__global__ void transpose_cs_k(const float* __restrict__ CS, float* __restrict__ X) {
  long idx = (long)blockIdx.x * 256 + threadIdx.x;   // < C*B*T*DC
  int d = (int)(idx & (DC_ - 1));
  long r = idx >> 8;                                  // c*(B*T) + bt
  int c = (int)(r / (B_ * T_));
  long bt = r % (B_ * T_);
  X[(bt * C_ + c) * DC_ + d] = CS[idx];
}

// ---------------- generic tiled GEMM: C = [resid +] [gelu(] A(f32 MxK) @ B(f32) [+bias] [)] ----------------
// 128x128 tile, 8x8 micro-tile per thread (split 4+4 quadrants), ds_read_b128 LDS reads.
// BT_: B accessed as B[n*Kd + k] (i.e. A @ B^T). Otherwise B[k*N + n].
// Batched over blockIdx.z with element strides sA/sB/sC/sBias/sRes.
// M % 128 == 0, N % 128 == 0, Kd % 16 == 0 (all shapes here satisfy this).
template<bool BT_, bool GELU_>
__global__ __launch_bounds__(256) void gemm_k(
    const float* __restrict__ A, const float* __restrict__ Bw, float* __restrict__ Cp,
    const float* __restrict__ bias, const float* __restrict__ resid,
    int M, int N, int Kd,
    long sA, long sB, long sC, long sBias, long sRes)
{
  int z = blockIdx.z;
  A  += (long)z * sA;
  Bw += (long)z * sB;
  if (bias)  bias  += (long)z * sBias;
  if (resid) resid += (long)z * sRes;
  long cbase = (long)z * sC;

  int n0 = blockIdx.x * 128;
  int m0 = blockIdx.y * 128;
  int tid = threadIdx.x;
  int tx = tid & 15, ty = tid >> 4;

  __shared__ alignas(16) float As[16][128];   // As[kk][mm] = A[m0+mm][k0+kk]
  __shared__ alignas(16) float Bs[16][128];   // Bs[kk][nn] = B[k0+kk][n0+nn]

  // staging indices
  const int smm = tid & 127;        // row (A) / n-row (B^T)
  const int skh = tid >> 7;         // k-half: 0 -> k 0..7, 1 -> k 8..15

  float acc[8][8] = {};

  for (int k0 = 0; k0 < Kd; k0 += 16) {
    // ---- stage A: 2 x float4 along K, scalar LDS writes at stride-1 mm (conflict-free)
    {
      const float* ap = A + (long)(m0 + smm) * Kd + (k0 + skh * 8);
      float4 a0 = *(const float4*)ap;
      float4 a1 = *(const float4*)(ap + 4);
      int kb = skh * 8;
      As[kb + 0][smm] = a0.x; As[kb + 1][smm] = a0.y;
      As[kb + 2][smm] = a0.z; As[kb + 3][smm] = a0.w;
      As[kb + 4][smm] = a1.x; As[kb + 5][smm] = a1.y;
      As[kb + 6][smm] = a1.z; As[kb + 7][smm] = a1.w;
    }
    // ---- stage B
    if (BT_) {
      const float* bp = Bw + (long)(n0 + smm) * Kd + (k0 + skh * 8);
      float4 b0 = *(const float4*)bp;
      float4 b1 = *(const float4*)(bp + 4);
      int kb = skh * 8;
      Bs[kb + 0][smm] = b0.x; Bs[kb + 1][smm] = b0.y;
      Bs[kb + 2][smm] = b0.z; Bs[kb + 3][smm] = b0.w;
      Bs[kb + 4][smm] = b1.x; Bs[kb + 5][smm] = b1.y;
      Bs[kb + 6][smm] = b1.z; Bs[kb + 7][smm] = b1.w;
    } else {
#pragma unroll
      for (int u = 0; u < 2; u++) {
        int e = tid + u * 256;          // float4 index within 16x128 tile
        int kk = e >> 5, nc = (e & 31) * 4;
        *(float4*)&Bs[kk][nc] = *(const float4*)&Bw[(long)(k0 + kk) * N + (n0 + nc)];
      }
    }
    __syncthreads();

#pragma unroll
    for (int kk = 0; kk < 16; kk++) {
      float a[8], bb[8];
      *(float4*)&a[0]  = *(const float4*)&As[kk][ty * 4];        // broadcast within wave
      *(float4*)&a[4]  = *(const float4*)&As[kk][64 + ty * 4];
      *(float4*)&bb[0] = *(const float4*)&Bs[kk][tx * 4];        // 2-way = free
      *(float4*)&bb[4] = *(const float4*)&Bs[kk][64 + tx * 4];
#pragma unroll
      for (int i = 0; i < 8; i++)
#pragma unroll
        for (int j = 0; j < 8; j++) acc[i][j] += a[i] * bb[j];
    }
    __syncthreads();
  }

  // ---- epilogue: float4 stores per (row, col-quadrant)
#pragma unroll
  for (int i = 0; i < 8; i++) {
    int mrow = m0 + ((i < 4) ? (ty * 4 + i) : (64 + ty * 4 + (i - 4)));
#pragma unroll
    for (int jh = 0; jh < 2; jh++) {
      int ncol = n0 + jh * 64 + tx * 4;
      float v[4];
#pragma unroll
      for (int j = 0; j < 4; j++) {
        float t = acc[i][jh * 4 + j];
        if (bias) t += bias[ncol + j];
        if (GELU_) t = gelu_f(t);
        if (resid) t += resid[(long)mrow * N + ncol + j];
        v[j] = t;
      }
      *(float4*)&Cp[cbase + (long)mrow * N + ncol] = *(float4*)v;
    }
  }
}

static inline void gemm_launch(hipStream_t st, bool bt, bool gelu,
    const float* A, const float* Bw, float* C, const float* bias, const float* resid,
    int M, int N, int Kd, long sA, long sB, long sC, long sBias, long sRes, int nz)
{
  dim3 g(N / 128, M / 128, nz), b(256, 1, 1);
  if (bt)
    gemm_k<true, false><<<g, b, 0, st>>>(A, Bw, C, bias, resid, M, N, Kd, sA, sB, sC, sBias, sRes);
  else if (gelu)
    gemm_k<false, true><<<g, b, 0, st>>>(A, Bw, C, bias, resid, M, N, Kd, sA, sB, sC, sBias, sRes);
  else
    gemm_k<false, false><<<g, b, 0, st>>>(A, Bw, C, bias, resid, M, N, Kd, sA, sB, sC, sBias, sRes);
}

extern "C" void kernel_launch(void* const* d_in, const int* in_sizes, int n_in,
                              void* d_out, int out_size, void* d_ws, size_t ws_size,
                              hipStream_t stream)
{
  (void)in_sizes; (void)n_in; (void)out_size; (void)ws_size;
  const int*   input_ids  = (const int*)  d_in[0];
  const float* tok_emb    = (const float*)d_in[1];
  const float* trunk_wq   = (const float*)d_in[2];
  const float* trunk_wk   = (const float*)d_in[3];
  const float* trunk_wv   = (const float*)d_in[4];
  const float* trunk_wo   = (const float*)d_in[5];
  const float* trunk_w1   = (const float*)d_in[6];
  const float* trunk_w2   = (const float*)d_in[7];
  const float* trunk_n1   = (const float*)d_in[8];
  const float* trunk_n2   = (const float*)d_in[9];
  const float* col_in_w   = (const float*)d_in[10];
  const float* col_in_b   = (const float*)d_in[11];
  const float* col_wq     = (const float*)d_in[12];
  const float* col_wk     = (const float*)d_in[13];
  const float* col_wv     = (const float*)d_in[14];
  const float* col_wo     = (const float*)d_in[15];
  const float* col_w1     = (const float*)d_in[16];
  const float* col_w2     = (const float*)d_in[17];
  const float* col_n1     = (const float*)d_in[18];
  const float* col_n2     = (const float*)d_in[19];
  const float* mrg_wq     = (const float*)d_in[20];
  const float* mrg_wk     = (const float*)d_in[21];
  const float* mrg_wv     = (const float*)d_in[22];
  const float* mrg_wo     = (const float*)d_in[23];
  const float* mrg_n      = (const float*)d_in[24];
  const float* out_proj   = (const float*)d_in[25];
  const float* final_norm = (const float*)d_in[26];

  // workspace layout (fp32): X,H,Q,K,V,CT,CS = 7 x 2M floats; FF aliases Q..CT (8M floats)
  // total = 14M floats = 56 MB
  const size_t M2 = (size_t)2 * 1024 * 1024;
  float* Xf  = (float*)d_ws;
  float* Hf  = Xf + M2;
  float* Qf  = Hf + M2;
  float* Kf  = Qf + M2;
  float* Vf  = Kf + M2;
  float* CTf = Vf + M2;
  float* CSf = CTf + M2;
  float* FFf = Qf;   // FF (B*T*DFF = 8M floats) lives only when Q/K/V/CT are dead

  const int BT = B_ * T_;            // 2048
  const float scale = 0.125f;        // 64^-0.5

  embed_k<<<BT, 256, 0, stream>>>(input_ids, tok_emb, Xf);

  // ---------------- trunk ----------------
  for (int l = 0; l < LT_; l++) {
    const float* wq = trunk_wq + (size_t)l * D_ * D_;
    const float* wk = trunk_wk + (size_t)l * D_ * D_;
    const float* wv = trunk_wv + (size_t)l * D_ * D_;
    const float* wo = trunk_wo + (size_t)l * D_ * D_;
    const float* w1 = trunk_w1 + (size_t)l * D_ * DFF_;
    const float* w2 = trunk_w2 + (size_t)l * DFF_ * D_;
    const float* n1 = trunk_n1 + (size_t)l * D_;
    const float* n2 = trunk_n2 + (size_t)l * D_;

    rmsnorm_k<<<BT, 256, 0, stream>>>(Xf, Hf, n1, D_, 1, 0);
    gemm_launch(stream, false, false, Hf, wq, Qf, nullptr, nullptr, BT, D_, D_, 0,0,0,0,0, 1);
    gemm_launch(stream, false, false, Hf, wk, Kf, nullptr, nullptr, BT, D_, D_, 0,0,0,0,0, 1);
    gemm_launch(stream, false, false, Hf, wv, Vf, nullptr, nullptr, BT, D_, D_, 0,0,0,0,0, 1);
    {
      long total = (long)BT * HT_ * 32;
      rope_k<<<(int)(total / 256), 256, 0, stream>>>(Qf, total, T_, HT_);
      rope_k<<<(int)(total / 256), 256, 0, stream>>>(Kf, total, T_, HT_);
    }
    attn_k<<<dim3(T_, HT_, B_), 256, 0, stream>>>(Qf, Kf, Vf, CTf, T_, HT_, scale);
    gemm_launch(stream, false, false, CTf, wo, Xf, nullptr, Xf, BT, D_, D_, 0,0,0,0,0, 1);
    rmsnorm_k<<<BT, 256, 0, stream>>>(Xf, Hf, n2, D_, 1, 0);
    gemm_launch(stream, false, true, Hf, w1, FFf, nullptr, nullptr, BT, DFF_, D_, 0,0,0,0,0, 1);
    gemm_launch(stream, false, false, FFf, w2, Xf, nullptr, Xf, BT, D_, DFF_, 0,0,0,0,0, 1);
  }

  // ---------------- column input projection: cs[c] = x @ col_in_w[c] + col_in_b[c] ----------------
  gemm_launch(stream, false, false, Xf, col_in_w, CSf, col_in_b, nullptr,
              BT, DC_, D_, 0, (long)D_ * DC_, (long)BT * DC_, DC_, 0, C_);

  // ---------------- column layers ----------------
  for (int l = 0; l < LC_; l++) {
    const float* cwq = col_wq + (size_t)l * DC_ * DC_;
    const float* cwk = col_wk + (size_t)l * DC_ * DC_;
    const float* cwv = col_wv + (size_t)l * DC_ * DC_;
    const float* cwo = col_wo + (size_t)l * DC_ * DC_;
    const float* cw1 = col_w1 + (size_t)l * DC_ * DFFC_;
    const float* cw2 = col_w2 + (size_t)l * DFFC_ * DC_;
    const long sW   = (long)LC_ * DC_ * DC_;
    const long sW1  = (long)LC_ * DC_ * DFFC_;
    const long sW2  = (long)LC_ * DFFC_ * DC_;
    const long sRow = (long)BT * DC_;

    rmsnorm_k<<<C_ * BT, 256, 0, stream>>>(CSf, Hf, col_n1 + (size_t)l * DC_, DC_, BT, (long)LC_ * DC_);
    gemm_launch(stream, false, false, Hf, cwq, Qf, nullptr, nullptr, BT, DC_, DC_, sRow, sW, sRow, 0, 0, C_);
    gemm_launch(stream, false, false, Hf, cwk, Kf, nullptr, nullptr, BT, DC_, DC_, sRow, sW, sRow, 0, 0, C_);
    gemm_launch(stream, false, false, Hf, cwv, Vf, nullptr, nullptr, BT, DC_, DC_, sRow, sW, sRow, 0, 0, C_);
    {
      long total = (long)C_ * BT * HC_ * 32;
      rope_k<<<(int)(total / 256), 256, 0, stream>>>(Qf, total, T_, HC_);
      rope_k<<<(int)(total / 256), 256, 0, stream>>>(Kf, total, T_, HC_);
    }
    attn_k<<<dim3(T_, HC_, C_ * B_), 256, 0, stream>>>(Qf, Kf, Vf, CTf, T_, HC_, scale);
    gemm_launch(stream, false, false, CTf, cwo, CSf, nullptr, CSf, BT, DC_, DC_, sRow, sW, sRow, 0, sRow, C_);
    rmsnorm_k<<<C_ * BT, 256, 0, stream>>>(CSf, Hf, col_n2 + (size_t)l * DC_, DC_, BT, (long)LC_ * DC_);
    gemm_launch(stream, false, true, Hf, cw1, FFf, nullptr, nullptr, BT, DFFC_, DC_,
                sRow, sW1, (long)BT * DFFC_, 0, 0, C_);
    gemm_launch(stream, false, false, FFf, cw2, CSf, nullptr, CSf, BT, DC_, DFFC_,
                (long)BT * DFFC_, sW2, sRow, 0, sRow, C_);

    if ((l + 1) % 2 == 0) {
      int mi = (l + 1) / 2 - 1;
      const float* mwq = mrg_wq + (size_t)mi * DC_ * DC_;
      const float* mwk = mrg_wk + (size_t)mi * DC_ * DC_;
      const float* mwv = mrg_wv + (size_t)mi * DC_ * DC_;
      const float* mwo = mrg_wo + (size_t)mi * DC_ * DC_;
      rmsnorm_k<<<C_ * BT, 256, 0, stream>>>(CSf, Hf, mrg_n + (size_t)mi * DC_, DC_, 1, 0);
      gemm_launch(stream, false, false, Hf, mwq, Qf, nullptr, nullptr, C_ * BT, DC_, DC_, 0,0,0,0,0, 1);
      gemm_launch(stream, false, false, Hf, mwk, Kf, nullptr, nullptr, C_ * BT, DC_, DC_, 0,0,0,0,0, 1);
      gemm_launch(stream, false, false, Hf, mwv, Vf, nullptr, nullptr, C_ * BT, DC_, DC_, 0,0,0,0,0, 1);
      merge_attn_k<<<BT * HC_, 64, 0, stream>>>(Qf, Kf, Vf, CTf, scale);
      gemm_launch(stream, false, false, CTf, mwo, CSf, nullptr, CSf, C_ * BT, DC_, DC_, 0,0,0,0,0, 1);
    }
  }

  // ---------------- head ----------------
  transpose_cs_k<<<(C_ * BT * DC_) / 256, 256, 0, stream>>>(CSf, Xf);
  gemm_launch(stream, false, false, Xf, out_proj, CTf, nullptr, nullptr, BT, D_, D_, 0,0,0,0,0, 1);
  rmsnorm_k<<<BT, 256, 0, stream>>>(CTf, Xf, final_norm, D_, 1, 0);
  // logits = normed @ tok_emb^T  (fp32 out)
  gemm_launch(stream, true, false, Xf, tok_emb, (float*)d_out, nullptr, nullptr, BT, VSZ_, D_, 0,0,0,0,0, 1);
}

// Round 4
// 9581.107 us; speedup vs baseline: 1.4194x; 1.4194x over previous
//
#include <hip/hip_runtime.h>
#include <hip/hip_bf16.h>
#include <math.h>

#define D_    1024
#define DFF_  4096
#define LT_   2
#define HT_   16
#define C_    4
#define DC_   256
#define DFFC_ 1024
#define LC_   4
#define HC_   4
#define B_    2
#define T_    1024
#define VSZ_  32000

__device__ __forceinline__ float gelu_f(float x) {
  // jax.nn.gelu default (approximate=True, tanh form)
  const float c = 0.7978845608028654f;
  return 0.5f * x * (1.f + tanhf(c * (x + 0.044715f * x * x * x)));
}

// ---------------- embedding gather: x[b,t,:] = tok_emb[ids[b,t],:] ----------------
__global__ void embed_k(const int* __restrict__ ids, const float* __restrict__ emb,
                        float* __restrict__ X) {
  int bt = blockIdx.x;
  int id = ids[bt];
  const float* e = emb + (long)id * D_;
  float* x = X + (long)bt * D_;
  for (int i = threadIdx.x; i < D_; i += 256) x[i] = e[i];
}

// ---------------- rmsnorm: one block per row ----------------
// weight selected per row-group: wp = W + (row/rowsPerGroup)*wStride
__global__ __launch_bounds__(256) void rmsnorm_k(const float* __restrict__ Xi,
    float* __restrict__ Y, const float* __restrict__ W, int Dn,
    int rowsPerGroup, long wStride)
{
  int r = blockIdx.x;
  const float* xp = Xi + (long)r * Dn;
  float* yp = Y + (long)r * Dn;
  const float* wp = W + (long)(r / rowsPerGroup) * wStride;
  __shared__ float red[256];
  float s = 0.f;
  for (int i = threadIdx.x; i < Dn; i += 256) { float v = xp[i]; s += v * v; }
  red[threadIdx.x] = s;
  __syncthreads();
  for (int w = 128; w; w >>= 1) {
    if (threadIdx.x < w) red[threadIdx.x] += red[threadIdx.x + w];
    __syncthreads();
  }
  float scale = 1.f / sqrtf(red[0] / (float)Dn + 1e-6f);
  for (int i = threadIdx.x; i < Dn; i += 256)
    yp[i] = xp[i] * scale * wp[i];
}

// ---------------- RoPE in-place on (NB, T, nh, 64); one thread per (row, pair) ----------------
__global__ void rope_k(float* __restrict__ Xq, long total, int T, int nh) {
  long idx = (long)blockIdx.x * 256 + threadIdx.x;
  if (idx >= total) return;
  int i = (int)(idx & 31);
  long rest = idx >> 5;
  int h = (int)(rest % nh);
  rest /= nh;                     // = nb*T + t
  int t = (int)(rest % T);
  float inv = powf(10000.f, -(float)(2 * i) / 64.f);
  float f = (float)t * inv;
  float c = cosf(f), s = sinf(f);
  float* p = Xq + (rest * (long)nh + h) * 64;
  float x1 = p[i], x2 = p[i + 32];
  p[i]      = x1 * c - x2 * s;
  p[i + 32] = x2 * c + x1 * s;
}

// ---------------- causal attention, online softmax; one block per (b,h,q) row ----------------
// Q/K/V/O layout: (NB, T, nh, 64)
// Wave-shuffle reductions (3 barriers/chunk) + PV parallelized over 4 j-groups.
__global__ __launch_bounds__(256) void attn_k(const float* __restrict__ Q,
    const float* __restrict__ Kt, const float* __restrict__ Vt,
    float* __restrict__ O, int T, int nh, float scale)
{
  int qi = blockIdx.x, h = blockIdx.y;
  long b = blockIdx.z;
  int tid = threadIdx.x;
  int lane = tid & 63, wv = tid >> 6;
  long rs = (long)nh * 64;
  const float* qp = Q + (b * T + qi) * rs + h * 64;
  __shared__ float qv[64], ov[64], pr[256], part[256], red4[4], sum4[4];
  if (tid < 64) { qv[tid] = qp[tid]; ov[tid] = 0.f; }
  __syncthreads();
  float m = -1e30f, l = 0.f;
  for (int k0 = 0; k0 <= qi; k0 += 256) {
    int jn = min(256, qi + 1 - k0);
    float s = -1e30f;
    if (tid < jn) {
      const float* kp = Kt + (b * T + k0 + tid) * rs + h * 64;
      float acc = 0.f;
#pragma unroll
      for (int d = 0; d < 64; d++) acc += qv[d] * kp[d];
      s = acc * scale;
    }
    // chunk max: wave shuffle + 4-way cross-wave combine
    float wm = s;
#pragma unroll
    for (int off = 32; off; off >>= 1) wm = fmaxf(wm, __shfl_xor(wm, off));
    if (lane == 0) red4[wv] = wm;
    __syncthreads();                               // A
    float nm = fmaxf(m, fmaxf(fmaxf(red4[0], red4[1]), fmaxf(red4[2], red4[3])));
    float p = (tid < jn) ? expf(s - nm) : 0.f;
    pr[tid] = p;
    float ws = p;
#pragma unroll
    for (int off = 32; off; off >>= 1) ws += __shfl_xor(ws, off);
    if (lane == 0) sum4[wv] = ws;
    __syncthreads();                               // B
    float csum = sum4[0] + sum4[1] + sum4[2] + sum4[3];
    float alpha = expf(m - nm);   // first chunk: exp(-huge) == 0, harmless
    l = l * alpha + csum;
    // PV: 4 j-groups of 64 lanes each, coalesced per j
    {
      int d = tid & 63, jg = tid >> 6;
      const float* vb = Vt + (b * T + k0) * rs + h * 64 + d;
      float acc = 0.f;
      for (int j = jg; j < jn; j += 4) acc += pr[j] * vb[(long)j * rs];
      part[tid] = acc;
    }
    __syncthreads();                               // C
    if (tid < 64)
      ov[tid] = ov[tid] * alpha + part[tid] + part[tid + 64] + part[tid + 128] + part[tid + 192];
    m = nm;
  }
  __syncthreads();
  if (tid < 64) O[(b * T + qi) * rs + h * 64 + tid] = ov[tid] / l;
}

// ---------------- cross-column merge attention: one wave per (b,t,h), softmax over 4 columns ----------------
// Q/K/V/O layout: (C, B, T, HC, 64)
__global__ __launch_bounds__(64) void merge_attn_k(const float* __restrict__ Q,
    const float* __restrict__ Kt, const float* __restrict__ Vt,
    float* __restrict__ O, float scale)
{
  int bid = blockIdx.x;              // ((b*T + t)*HC + h)
  int h = bid & (HC_ - 1);
  int t = (bid >> 2) & (T_ - 1);
  int b = bid >> 12;
  int d = threadIdx.x;
  long base[C_];
  float q[C_], k[C_], v[C_];
#pragma unroll
  for (int c = 0; c < C_; c++) {
    base[c] = ((((long)c * B_ + b) * T_ + t) * HC_ + h) * 64 + d;
    q[c] = Q[base[c]]; k[c] = Kt[base[c]]; v[c] = Vt[base[c]];
  }
  float s[C_][C_];
#pragma unroll
  for (int i = 0; i < C_; i++)
#pragma unroll
    for (int j = 0; j < C_; j++) {
      float p = q[i] * k[j];
#pragma unroll
      for (int off = 32; off; off >>= 1) p += __shfl_xor(p, off);
      s[i][j] = p * scale;
    }
#pragma unroll
  for (int i = 0; i < C_; i++) {
    float mx = fmaxf(fmaxf(s[i][0], s[i][1]), fmaxf(s[i][2], s[i][3]));
    float e0 = expf(s[i][0] - mx), e1 = expf(s[i][1] - mx),
          e2 = expf(s[i][2] - mx), e3 = expf(s[i][3] - mx);
    float inv = 1.f / (e0 + e1 + e2 + e3);
    O[base[i]] = (e0 * v[0] + e1 * v[1] + e2 * v[2] + e3 * v[3]) * inv;
  }
}

// ---------------- transpose (C,B,T,DC) -> (B,T,C*DC) ----------------
__global__ void transpose_cs_k(const float* __restrict__ CS, float* __restrict__ X) {
  long idx = (long)blockIdx.x * 256 + threadIdx.x;   // < C*B*T*DC
  int d = (int)(idx & (DC_ - 1));
  long r = idx >> 8;                                  // c*(B*T) + bt
  int c = (int)(r / (B_ * T_));
  long bt = r % (B_ * T_);
  X[(bt * C_ + c) * DC_ + d] = CS[idx];
}

// ---------------- 128x128 tiled GEMM (for grids >= 256 blocks) ----------------
// 8x8 micro-tile per thread (split 4+4 quadrants), ds_read_b128 LDS reads.
// BT_: B accessed as B[n*Kd + k] (i.e. A @ B^T). Otherwise B[k*N + n].
// Batched over blockIdx.z with element strides sA/sB/sC/sBias/sRes.
template<bool BT_, bool GELU_>
__global__ __launch_bounds__(256) void gemm_k(
    const float* __restrict__ A, const float* __restrict__ Bw, float* __restrict__ Cp,
    const float* __restrict__ bias, const float* __restrict__ resid,
    int M, int N, int Kd,
    long sA, long sB, long sC, long sBias, long sRes)
{
  int z = blockIdx.z;
  A  += (long)z * sA;
  Bw += (long)z * sB;
  if (bias)  bias  += (long)z * sBias;
  if (resid) resid += (long)z * sRes;
  long cbase = (long)z * sC;

  int n0 = blockIdx.x * 128;
  int m0 = blockIdx.y * 128;
  int tid = threadIdx.x;
  int tx = tid & 15, ty = tid >> 4;

  __shared__ alignas(16) float As[16][128];   // As[kk][mm] = A[m0+mm][k0+kk]
  __shared__ alignas(16) float Bs[16][128];   // Bs[kk][nn] = B[k0+kk][n0+nn]

  // staging indices
  const int smm = tid & 127;        // row (A) / n-row (B^T)
  const int skh = tid >> 7;         // k-half: 0 -> k 0..7, 1 -> k 8..15

  float acc[8][8] = {};

  for (int k0 = 0; k0 < Kd; k0 += 16) {
    // ---- stage A: 2 x float4 along K, scalar LDS writes at stride-1 mm (conflict-free)
    {
      const float* ap = A + (long)(m0 + smm) * Kd + (k0 + skh * 8);
      float4 a0 = *(const float4*)ap;
      float4 a1 = *(const float4*)(ap + 4);
      int kb = skh * 8;
      As[kb + 0][smm] = a0.x; As[kb + 1][smm] = a0.y;
      As[kb + 2][smm] = a0.z; As[kb + 3][smm] = a0.w;
      As[kb + 4][smm] = a1.x; As[kb + 5][smm] = a1.y;
      As[kb + 6][smm] = a1.z; As[kb + 7][smm] = a1.w;
    }
    // ---- stage B
    if (BT_) {
      const float* bp = Bw + (long)(n0 + smm) * Kd + (k0 + skh * 8);
      float4 b0 = *(const float4*)bp;
      float4 b1 = *(const float4*)(bp + 4);
      int kb = skh * 8;
      Bs[kb + 0][smm] = b0.x; Bs[kb + 1][smm] = b0.y;
      Bs[kb + 2][smm] = b0.z; Bs[kb + 3][smm] = b0.w;
      Bs[kb + 4][smm] = b1.x; Bs[kb + 5][smm] = b1.y;
      Bs[kb + 6][smm] = b1.z; Bs[kb + 7][smm] = b1.w;
    } else {
#pragma unroll
      for (int u = 0; u < 2; u++) {
        int e = tid + u * 256;          // float4 index within 16x128 tile
        int kk = e >> 5, nc = (e & 31) * 4;
        *(float4*)&Bs[kk][nc] = *(const float4*)&Bw[(long)(k0 + kk) * N + (n0 + nc)];
      }
    }
    __syncthreads();

#pragma unroll
    for (int kk = 0; kk < 16; kk++) {
      float a[8], bb[8];
      *(float4*)&a[0]  = *(const float4*)&As[kk][ty * 4];        // broadcast within wave
      *(float4*)&a[4]  = *(const float4*)&As[kk][64 + ty * 4];
      *(float4*)&bb[0] = *(const float4*)&Bs[kk][tx * 4];        // 2-way = free
      *(float4*)&bb[4] = *(const float4*)&Bs[kk][64 + tx * 4];
#pragma unroll
      for (int i = 0; i < 8; i++)
#pragma unroll
        for (int j = 0; j < 8; j++) acc[i][j] += a[i] * bb[j];
    }
    __syncthreads();
  }

  // ---- epilogue: float4 stores per (row, col-quadrant)
#pragma unroll
  for (int i = 0; i < 8; i++) {
    int mrow = m0 + ((i < 4) ? (ty * 4 + i) : (64 + ty * 4 + (i - 4)));
#pragma unroll
    for (int jh = 0; jh < 2; jh++) {
      int ncol = n0 + jh * 64 + tx * 4;
      float v[4];
#pragma unroll
      for (int j = 0; j < 4; j++) {
        float t = acc[i][jh * 4 + j];
        if (bias) t += bias[ncol + j];
        if (GELU_) t = gelu_f(t);
        if (resid) t += resid[(long)mrow * N + ncol + j];
        v[j] = t;
      }
      *(float4*)&Cp[cbase + (long)mrow * N + ncol] = *(float4*)v;
    }
  }
}

// ---------------- 64x64 tiled GEMM (for small grids; keeps >= 512 blocks) ----------------
// 4x4 micro-tile per thread, ds_read_b128 LDS reads, conflict-free staging.
template<bool BT_, bool GELU_>
__global__ __launch_bounds__(256) void gemm64_k(
    const float* __restrict__ A, const float* __restrict__ Bw, float* __restrict__ Cp,
    const float* __restrict__ bias, const float* __restrict__ resid,
    int M, int N, int Kd,
    long sA, long sB, long sC, long sBias, long sRes)
{
  int z = blockIdx.z;
  A  += (long)z * sA;
  Bw += (long)z * sB;
  if (bias)  bias  += (long)z * sBias;
  if (resid) resid += (long)z * sRes;
  long cbase = (long)z * sC;

  int n0 = blockIdx.x * 64;
  int m0 = blockIdx.y * 64;
  int tid = threadIdx.x;
  int tx = tid & 15, ty = tid >> 4;

  __shared__ alignas(16) float As[16][64];   // As[kk][mm]
  __shared__ alignas(16) float Bs[16][64];   // Bs[kk][nn]

  // staging: 16x64 tile = 1024 floats = 256 threads x float4 along K
  const int smm = tid >> 2;          // 0..63 row
  const int sk4 = (tid & 3) * 4;     // k offset 0/4/8/12

  float acc[4][4] = {};

  for (int k0 = 0; k0 < Kd; k0 += 16) {
    {
      const float* ap = A + (long)(m0 + smm) * Kd + (k0 + sk4);
      float4 a0 = *(const float4*)ap;
      As[sk4 + 0][smm] = a0.x; As[sk4 + 1][smm] = a0.y;
      As[sk4 + 2][smm] = a0.z; As[sk4 + 3][smm] = a0.w;
    }
    if (BT_) {
      const float* bp = Bw + (long)(n0 + smm) * Kd + (k0 + sk4);
      float4 b0 = *(const float4*)bp;
      Bs[sk4 + 0][smm] = b0.x; Bs[sk4 + 1][smm] = b0.y;
      Bs[sk4 + 2][smm] = b0.z; Bs[sk4 + 3][smm] = b0.w;
    } else {
      int kk = tid >> 4, nc = (tid & 15) * 4;
      *(float4*)&Bs[kk][nc] = *(const float4*)&Bw[(long)(k0 + kk) * N + (n0 + nc)];
    }
    __syncthreads();

#pragma unroll
    for (int kk = 0; kk < 16; kk++) {
      float a[4], bb[4];
      *(float4*)&a[0]  = *(const float4*)&As[kk][ty * 4];
      *(float4*)&bb[0] = *(const float4*)&Bs[kk][tx * 4];
#pragma unroll
      for (int i = 0; i < 4; i++)
#pragma unroll
        for (int j = 0; j < 4; j++) acc[i][j] += a[i] * bb[j];
    }
    __syncthreads();
  }

#pragma unroll
  for (int i = 0; i < 4; i++) {
    int mrow = m0 + ty * 4 + i;
    int ncol = n0 + tx * 4;
    float v[4];
#pragma unroll
    for (int j = 0; j < 4; j++) {
      float t = acc[i][j];
      if (bias) t += bias[ncol + j];
      if (GELU_) t = gelu_f(t);
      if (resid) t += resid[(long)mrow * N + ncol + j];
      v[j] = t;
    }
    *(float4*)&Cp[cbase + (long)mrow * N + ncol] = *(float4*)v;
  }
}

static inline void gemm_launch(hipStream_t st, bool bt, bool gelu,
    const float* A, const float* Bw, float* C, const float* bias, const float* resid,
    int M, int N, int Kd, long sA, long sB, long sC, long sBias, long sRes, int nz)
{
  long blocks128 = (long)(N / 128) * (M / 128) * nz;
  bool use128 = (N % 128 == 0) && (M % 128 == 0) && blocks128 >= 256;
  if (use128) {
    dim3 g(N / 128, M / 128, nz), b(256, 1, 1);
    if (bt)
      gemm_k<true, false><<<g, b, 0, st>>>(A, Bw, C, bias, resid, M, N, Kd, sA, sB, sC, sBias, sRes);
    else if (gelu)
      gemm_k<false, true><<<g, b, 0, st>>>(A, Bw, C, bias, resid, M, N, Kd, sA, sB, sC, sBias, sRes);
    else
      gemm_k<false, false><<<g, b, 0, st>>>(A, Bw, C, bias, resid, M, N, Kd, sA, sB, sC, sBias, sRes);
  } else {
    dim3 g(N / 64, M / 64, nz), b(256, 1, 1);
    if (bt)
      gemm64_k<true, false><<<g, b, 0, st>>>(A, Bw, C, bias, resid, M, N, Kd, sA, sB, sC, sBias, sRes);
    else if (gelu)
      gemm64_k<false, true><<<g, b, 0, st>>>(A, Bw, C, bias, resid, M, N, Kd, sA, sB, sC, sBias, sRes);
    else
      gemm64_k<false, false><<<g, b, 0, st>>>(A, Bw, C, bias, resid, M, N, Kd, sA, sB, sC, sBias, sRes);
  }
}

extern "C" void kernel_launch(void* const* d_in, const int* in_sizes, int n_in,
                              void* d_out, int out_size, void* d_ws, size_t ws_size,
                              hipStream_t stream)
{
  (void)in_sizes; (void)n_in; (void)out_size; (void)ws_size;
  const int*   input_ids  = (const int*)  d_in[0];
  const float* tok_emb    = (const float*)d_in[1];
  const float* trunk_wq   = (const float*)d_in[2];
  const float* trunk_wk   = (const float*)d_in[3];
  const float* trunk_wv   = (const float*)d_in[4];
  const float* trunk_wo   = (const float*)d_in[5];
  const float* trunk_w1   = (const float*)d_in[6];
  const float* trunk_w2   = (const float*)d_in[7];
  const float* trunk_n1   = (const float*)d_in[8];
  const float* trunk_n2   = (const float*)d_in[9];
  const float* col_in_w   = (const float*)d_in[10];
  const float* col_in_b   = (const float*)d_in[11];
  const float* col_wq     = (const float*)d_in[12];
  const float* col_wk     = (const float*)d_in[13];
  const float* col_wv     = (const float*)d_in[14];
  const float* col_wo     = (const float*)d_in[15];
  const float* col_w1     = (const float*)d_in[16];
  const float* col_w2     = (const float*)d_in[17];
  const float* col_n1     = (const float*)d_in[18];
  const float* col_n2     = (const float*)d_in[19];
  const float* mrg_wq     = (const float*)d_in[20];
  const float* mrg_wk     = (const float*)d_in[21];
  const float* mrg_wv     = (const float*)d_in[22];
  const float* mrg_wo     = (const float*)d_in[23];
  const float* mrg_n      = (const float*)d_in[24];
  const float* out_proj   = (const float*)d_in[25];
  const float* final_norm = (const float*)d_in[26];

  // workspace layout (fp32): X,H,Q,K,V,CT,CS = 7 x 2M floats; FF aliases Q..CT (8M floats)
  // total = 14M floats = 56 MB
  const size_t M2 = (size_t)2 * 1024 * 1024;
  float* Xf  = (float*)d_ws;
  float* Hf  = Xf + M2;
  float* Qf  = Hf + M2;
  float* Kf  = Qf + M2;
  float* Vf  = Kf + M2;
  float* CTf = Vf + M2;
  float* CSf = CTf + M2;
  float* FFf = Qf;   // FF (B*T*DFF = 8M floats) lives only when Q/K/V/CT are dead

  const int BT = B_ * T_;            // 2048
  const float scale = 0.125f;        // 64^-0.5

  embed_k<<<BT, 256, 0, stream>>>(input_ids, tok_emb, Xf);

  // ---------------- trunk ----------------
  for (int l = 0; l < LT_; l++) {
    const float* wq = trunk_wq + (size_t)l * D_ * D_;
    const float* wk = trunk_wk + (size_t)l * D_ * D_;
    const float* wv = trunk_wv + (size_t)l * D_ * D_;
    const float* wo = trunk_wo + (size_t)l * D_ * D_;
    const float* w1 = trunk_w1 + (size_t)l * D_ * DFF_;
    const float* w2 = trunk_w2 + (size_t)l * DFF_ * D_;
    const float* n1 = trunk_n1 + (size_t)l * D_;
    const float* n2 = trunk_n2 + (size_t)l * D_;

    rmsnorm_k<<<BT, 256, 0, stream>>>(Xf, Hf, n1, D_, 1, 0);
    gemm_launch(stream, false, false, Hf, wq, Qf, nullptr, nullptr, BT, D_, D_, 0,0,0,0,0, 1);
    gemm_launch(stream, false, false, Hf, wk, Kf, nullptr, nullptr, BT, D_, D_, 0,0,0,0,0, 1);
    gemm_launch(stream, false, false, Hf, wv, Vf, nullptr, nullptr, BT, D_, D_, 0,0,0,0,0, 1);
    {
      long total = (long)BT * HT_ * 32;
      rope_k<<<(int)(total / 256), 256, 0, stream>>>(Qf, total, T_, HT_);
      rope_k<<<(int)(total / 256), 256, 0, stream>>>(Kf, total, T_, HT_);
    }
    attn_k<<<dim3(T_, HT_, B_), 256, 0, stream>>>(Qf, Kf, Vf, CTf, T_, HT_, scale);
    gemm_launch(stream, false, false, CTf, wo, Xf, nullptr, Xf, BT, D_, D_, 0,0,0,0,0, 1);
    rmsnorm_k<<<BT, 256, 0, stream>>>(Xf, Hf, n2, D_, 1, 0);
    gemm_launch(stream, false, true, Hf, w1, FFf, nullptr, nullptr, BT, DFF_, D_, 0,0,0,0,0, 1);
    gemm_launch(stream, false, false, FFf, w2, Xf, nullptr, Xf, BT, D_, DFF_, 0,0,0,0,0, 1);
  }

  // ---------------- column input projection: cs[c] = x @ col_in_w[c] + col_in_b[c] ----------------
  gemm_launch(stream, false, false, Xf, col_in_w, CSf, col_in_b, nullptr,
              BT, DC_, D_, 0, (long)D_ * DC_, (long)BT * DC_, DC_, 0, C_);

  // ---------------- column layers ----------------
  for (int l = 0; l < LC_; l++) {
    const float* cwq = col_wq + (size_t)l * DC_ * DC_;
    const float* cwk = col_wk + (size_t)l * DC_ * DC_;
    const float* cwv = col_wv + (size_t)l * DC_ * DC_;
    const float* cwo = col_wo + (size_t)l * DC_ * DC_;
    const float* cw1 = col_w1 + (size_t)l * DC_ * DFFC_;
    const float* cw2 = col_w2 + (size_t)l * DFFC_ * DC_;
    const long sW   = (long)LC_ * DC_ * DC_;
    const long sW1  = (long)LC_ * DC_ * DFFC_;
    const long sW2  = (long)LC_ * DFFC_ * DC_;
    const long sRow = (long)BT * DC_;

    rmsnorm_k<<<C_ * BT, 256, 0, stream>>>(CSf, Hf, col_n1 + (size_t)l * DC_, DC_, BT, (long)LC_ * DC_);
    gemm_launch(stream, false, false, Hf, cwq, Qf, nullptr, nullptr, BT, DC_, DC_, sRow, sW, sRow, 0, 0, C_);
    gemm_launch(stream, false, false, Hf, cwk, Kf, nullptr, nullptr, BT, DC_, DC_, sRow, sW, sRow, 0, 0, C_);
    gemm_launch(stream, false, false, Hf, cwv, Vf, nullptr, nullptr, BT, DC_, DC_, sRow, sW, sRow, 0, 0, C_);
    {
      long total = (long)C_ * BT * HC_ * 32;
      rope_k<<<(int)(total / 256), 256, 0, stream>>>(Qf, total, T_, HC_);
      rope_k<<<(int)(total / 256), 256, 0, stream>>>(Kf, total, T_, HC_);
    }
    attn_k<<<dim3(T_, HC_, C_ * B_), 256, 0, stream>>>(Qf, Kf, Vf, CTf, T_, HC_, scale);
    gemm_launch(stream, false, false, CTf, cwo, CSf, nullptr, CSf, BT, DC_, DC_, sRow, sW, sRow, 0, sRow, C_);
    rmsnorm_k<<<C_ * BT, 256, 0, stream>>>(CSf, Hf, col_n2 + (size_t)l * DC_, DC_, BT, (long)LC_ * DC_);
    gemm_launch(stream, false, true, Hf, cw1, FFf, nullptr, nullptr, BT, DFFC_, DC_,
                sRow, sW1, (long)BT * DFFC_, 0, 0, C_);
    gemm_launch(stream, false, false, FFf, cw2, CSf, nullptr, CSf, BT, DC_, DFFC_,
                (long)BT * DFFC_, sW2, sRow, 0, sRow, C_);

    if ((l + 1) % 2 == 0) {
      int mi = (l + 1) / 2 - 1;
      const float* mwq = mrg_wq + (size_t)mi * DC_ * DC_;
      const float* mwk = mrg_wk + (size_t)mi * DC_ * DC_;
      const float* mwv = mrg_wv + (size_t)mi * DC_ * DC_;
      const float* mwo = mrg_wo + (size_t)mi * DC_ * DC_;
      rmsnorm_k<<<C_ * BT, 256, 0, stream>>>(CSf, Hf, mrg_n + (size_t)mi * DC_, DC_, 1, 0);
      gemm_launch(stream, false, false, Hf, mwq, Qf, nullptr, nullptr, C_ * BT, DC_, DC_, 0,0,0,0,0, 1);
      gemm_launch(stream, false, false, Hf, mwk, Kf, nullptr, nullptr, C_ * BT, DC_, DC_, 0,0,0,0,0, 1);
      gemm_launch(stream, false, false, Hf, mwv, Vf, nullptr, nullptr, C_ * BT, DC_, DC_, 0,0,0,0,0, 1);
      merge_attn_k<<<BT * HC_, 64, 0, stream>>>(Qf, Kf, Vf, CTf, scale);
      gemm_launch(stream, false, false, CTf, mwo, CSf, nullptr, CSf, C_ * BT, DC_, DC_, 0,0,0,0,0, 1);
    }
  }

  // ---------------- head ----------------
  transpose_cs_k<<<(C_ * BT * DC_) / 256, 256, 0, stream>>>(CSf, Xf);
  gemm_launch(stream, false, false, Xf, out_proj, CTf, nullptr, nullptr, BT, D_, D_, 0,0,0,0,0, 1);
  rmsnorm_k<<<BT, 256, 0, stream>>>(CTf, Xf, final_norm, D_, 1, 0);
  // logits = normed @ tok_emb^T  (fp32 out)
  gemm_launch(stream, true, false, Xf, tok_emb, (float*)d_out, nullptr, nullptr, BT, VSZ_, D_, 0,0,0,0,0, 1);
}

// Round 5
// 8906.602 us; speedup vs baseline: 1.5269x; 1.0757x over previous
//
#include <hip/hip_runtime.h>
#include <hip/hip_bf16.h>
#include <math.h>

#define D_    1024
#define DFF_  4096
#define LT_   2
#define HT_   16
#define C_    4
#define DC_   256
#define DFFC_ 1024
#define LC_   4
#define HC_   4
#define B_    2
#define T_    1024
#define VSZ_  32000

typedef __attribute__((ext_vector_type(8))) short bfrag;   // 8 bf16 = 4 VGPRs
typedef __attribute__((ext_vector_type(4))) float f4acc;   // 4 fp32 accum

__device__ __forceinline__ float gelu_f(float x) {
  const float c = 0.7978845608028654f;
  return 0.5f * x * (1.f + tanhf(c * (x + 0.044715f * x * x * x)));
}

// fp32 -> bf16 round-to-nearest-even (bit trick), and back
__device__ __forceinline__ unsigned short f2bf(float x) {
  unsigned u = __float_as_uint(x);
  return (unsigned short)((u + 0x7FFFu + ((u >> 16) & 1u)) >> 16);
}
__device__ __forceinline__ float bf2f(unsigned short h) {
  return __uint_as_float(((unsigned)h) << 16);
}

// ---------------- embedding gather ----------------
__global__ void embed_k(const int* __restrict__ ids, const float* __restrict__ emb,
                        float* __restrict__ X) {
  int bt = blockIdx.x;
  int id = ids[bt];
  const float* e = emb + (long)id * D_;
  float* x = X + (long)bt * D_;
  for (int i = threadIdx.x; i < D_; i += 256) x[i] = e[i];
}

// ---------------- rmsnorm ----------------
__global__ __launch_bounds__(256) void rmsnorm_k(const float* __restrict__ Xi,
    float* __restrict__ Y, const float* __restrict__ W, int Dn,
    int rowsPerGroup, long wStride)
{
  int r = blockIdx.x;
  const float* xp = Xi + (long)r * Dn;
  float* yp = Y + (long)r * Dn;
  const float* wp = W + (long)(r / rowsPerGroup) * wStride;
  __shared__ float red[256];
  float s = 0.f;
  for (int i = threadIdx.x; i < Dn; i += 256) { float v = xp[i]; s += v * v; }
  red[threadIdx.x] = s;
  __syncthreads();
  for (int w = 128; w; w >>= 1) {
    if (threadIdx.x < w) red[threadIdx.x] += red[threadIdx.x + w];
    __syncthreads();
  }
  float scale = 1.f / sqrtf(red[0] / (float)Dn + 1e-6f);
  for (int i = threadIdx.x; i < Dn; i += 256)
    yp[i] = xp[i] * scale * wp[i];
}

// ---------------- RoPE ----------------
__global__ void rope_k(float* __restrict__ Xq, long total, int T, int nh) {
  long idx = (long)blockIdx.x * 256 + threadIdx.x;
  if (idx >= total) return;
  int i = (int)(idx & 31);
  long rest = idx >> 5;
  int h = (int)(rest % nh);
  rest /= nh;
  int t = (int)(rest % T);
  float inv = powf(10000.f, -(float)(2 * i) / 64.f);
  float f = (float)t * inv;
  float c = cosf(f), s = sinf(f);
  float* p = Xq + (rest * (long)nh + h) * 64;
  float x1 = p[i], x2 = p[i + 32];
  p[i]      = x1 * c - x2 * s;
  p[i + 32] = x2 * c + x1 * s;
}

// ---------------- causal attention (unchanged this round) ----------------
__global__ __launch_bounds__(256) void attn_k(const float* __restrict__ Q,
    const float* __restrict__ Kt, const float* __restrict__ Vt,
    float* __restrict__ O, int T, int nh, float scale)
{
  int qi = blockIdx.x, h = blockIdx.y;
  long b = blockIdx.z;
  int tid = threadIdx.x;
  int lane = tid & 63, wv = tid >> 6;
  long rs = (long)nh * 64;
  const float* qp = Q + (b * T + qi) * rs + h * 64;
  __shared__ float qv[64], ov[64], pr[256], part[256], red4[4], sum4[4];
  if (tid < 64) { qv[tid] = qp[tid]; ov[tid] = 0.f; }
  __syncthreads();
  float m = -1e30f, l = 0.f;
  for (int k0 = 0; k0 <= qi; k0 += 256) {
    int jn = min(256, qi + 1 - k0);
    float s = -1e30f;
    if (tid < jn) {
      const float* kp = Kt + (b * T + k0 + tid) * rs + h * 64;
      float acc = 0.f;
#pragma unroll
      for (int d = 0; d < 64; d++) acc += qv[d] * kp[d];
      s = acc * scale;
    }
    float wm = s;
#pragma unroll
    for (int off = 32; off; off >>= 1) wm = fmaxf(wm, __shfl_xor(wm, off));
    if (lane == 0) red4[wv] = wm;
    __syncthreads();
    float nm = fmaxf(m, fmaxf(fmaxf(red4[0], red4[1]), fmaxf(red4[2], red4[3])));
    float p = (tid < jn) ? expf(s - nm) : 0.f;
    pr[tid] = p;
    float ws = p;
#pragma unroll
    for (int off = 32; off; off >>= 1) ws += __shfl_xor(ws, off);
    if (lane == 0) sum4[wv] = ws;
    __syncthreads();
    float csum = sum4[0] + sum4[1] + sum4[2] + sum4[3];
    float alpha = expf(m - nm);
    l = l * alpha + csum;
    {
      int d = tid & 63, jg = tid >> 6;
      const float* vb = Vt + (b * T + k0) * rs + h * 64 + d;
      float acc = 0.f;
      for (int j = jg; j < jn; j += 4) acc += pr[j] * vb[(long)j * rs];
      part[tid] = acc;
    }
    __syncthreads();
    if (tid < 64)
      ov[tid] = ov[tid] * alpha + part[tid] + part[tid + 64] + part[tid + 128] + part[tid + 192];
    m = nm;
  }
  __syncthreads();
  if (tid < 64) O[(b * T + qi) * rs + h * 64 + tid] = ov[tid] / l;
}

// ---------------- cross-column merge attention ----------------
__global__ __launch_bounds__(64) void merge_attn_k(const float* __restrict__ Q,
    const float* __restrict__ Kt, const float* __restrict__ Vt,
    float* __restrict__ O, float scale)
{
  int bid = blockIdx.x;
  int h = bid & (HC_ - 1);
  int t = (bid >> 2) & (T_ - 1);
  int b = bid >> 12;
  int d = threadIdx.x;
  long base[C_];
  float q[C_], k[C_], v[C_];
#pragma unroll
  for (int c = 0; c < C_; c++) {
    base[c] = ((((long)c * B_ + b) * T_ + t) * HC_ + h) * 64 + d;
    q[c] = Q[base[c]]; k[c] = Kt[base[c]]; v[c] = Vt[base[c]];
  }
  float s[C_][C_];
#pragma unroll
  for (int i = 0; i < C_; i++)
#pragma unroll
    for (int j = 0; j < C_; j++) {
      float p = q[i] * k[j];
#pragma unroll
      for (int off = 32; off; off >>= 1) p += __shfl_xor(p, off);
      s[i][j] = p * scale;
    }
#pragma unroll
  for (int i = 0; i < C_; i++) {
    float mx = fmaxf(fmaxf(s[i][0], s[i][1]), fmaxf(s[i][2], s[i][3]));
    float e0 = expf(s[i][0] - mx), e1 = expf(s[i][1] - mx),
          e2 = expf(s[i][2] - mx), e3 = expf(s[i][3] - mx);
    float inv = 1.f / (e0 + e1 + e2 + e3);
    O[base[i]] = (e0 * v[0] + e1 * v[1] + e2 * v[2] + e3 * v[3]) * inv;
  }
}

// ---------------- transpose (C,B,T,DC) -> (B,T,C*DC) ----------------
__global__ void transpose_cs_k(const float* __restrict__ CS, float* __restrict__ X) {
  long idx = (long)blockIdx.x * 256 + threadIdx.x;
  int d = (int)(idx & (DC_ - 1));
  long r = idx >> 8;
  int c = (int)(r / (B_ * T_));
  long bt = r % (B_ * T_);
  X[(bt * C_ + c) * DC_ + d] = CS[idx];
}

// ---------------- MFMA split-bf16 GEMM: C = [resid +][gelu(] A @ B(/B^T) [+bias][)] ----------------
// 128x128 tile, 256 threads = 4 waves (2x2), wave-tile 64x64 = 4x4 frags of 16x16.
// Split precision: A = Ah + Al (bf16), B = Bh + Bl; acc += AhBh + AhBl + AlBh  (~fp32 accuracy).
// LDS planes [row][32] bf16 (64B rows). k-chunk c (8 elems) stored rotated: cp = (c + (row>>1)) & 3.
// Same rotation applied on fragment reads -> consistent; rotation makes staging writes AND frag
// reads uniform across the 8 LDS 16B-slots (conflict-free b128).
// Requires M%128==0, N%128==0, Kd%32==0 (all shapes here satisfy this).
template<bool BT_, bool GELU_>
__global__ __launch_bounds__(256, 2) void gemm_mfma_k(
    const float* __restrict__ A, const float* __restrict__ Bw, float* __restrict__ Cp,
    const float* __restrict__ bias, const float* __restrict__ resid,
    int M, int N, int Kd,
    long sA, long sB, long sC, long sBias, long sRes)
{
  int z = blockIdx.z;
  A  += (long)z * sA;
  Bw += (long)z * sB;
  if (bias)  bias  += (long)z * sBias;
  if (resid) resid += (long)z * sRes;
  long cbase = (long)z * sC;

  const int n0 = blockIdx.x * 128;
  const int m0 = blockIdx.y * 128;
  const int tid = threadIdx.x;
  const int lane = tid & 63, wv = tid >> 6;
  const int wm = (wv >> 1) * 64, wn = (wv & 1) * 64;
  const int fr = lane & 15, fg = lane >> 4;     // frag row(A)/col(B), k-group

  __shared__ alignas(16) unsigned short Ah[128][32];
  __shared__ alignas(16) unsigned short Al[128][32];
  __shared__ alignas(16) unsigned short Bh[128][32];
  __shared__ alignas(16) unsigned short Bl[128][32];

  f4acc acc[4][4];
#pragma unroll
  for (int i = 0; i < 4; i++)
#pragma unroll
    for (int j = 0; j < 4; j++) acc[i][j] = (f4acc)0.f;

  const int sm = tid & 127;   // staging row (A-row / B^T n-row / B n)
  const int sq = tid >> 7;    // 0/1

  for (int k0 = 0; k0 < Kd; k0 += 32) {
    // ---- stage A: rows, 2 k-chunks of 8 per thread
#pragma unroll
    for (int i = 0; i < 2; i++) {
      int c = sq + 2 * i;
      const float* ap = A + (long)(m0 + sm) * Kd + (k0 + c * 8);
      float4 f0 = *(const float4*)ap;
      float4 f1 = *(const float4*)(ap + 4);
      float v[8] = {f0.x, f0.y, f0.z, f0.w, f1.x, f1.y, f1.z, f1.w};
      unsigned short h8[8], l8[8];
#pragma unroll
      for (int j = 0; j < 8; j++) {
        h8[j] = f2bf(v[j]);
        l8[j] = f2bf(v[j] - bf2f(h8[j]));
      }
      int cp = (c + (sm >> 1)) & 3;
      *(uint4*)&Ah[sm][cp * 8] = *(uint4*)h8;
      *(uint4*)&Al[sm][cp * 8] = *(uint4*)l8;
    }
    // ---- stage B
    if (BT_) {
#pragma unroll
      for (int i = 0; i < 2; i++) {
        int c = sq + 2 * i;
        const float* bp = Bw + (long)(n0 + sm) * Kd + (k0 + c * 8);
        float4 f0 = *(const float4*)bp;
        float4 f1 = *(const float4*)(bp + 4);
        float v[8] = {f0.x, f0.y, f0.z, f0.w, f1.x, f1.y, f1.z, f1.w};
        unsigned short h8[8], l8[8];
#pragma unroll
        for (int j = 0; j < 8; j++) {
          h8[j] = f2bf(v[j]);
          l8[j] = f2bf(v[j] - bf2f(h8[j]));
        }
        int cp = (c + (sm >> 1)) & 3;
        *(uint4*)&Bh[sm][cp * 8] = *(uint4*)h8;
        *(uint4*)&Bl[sm][cp * 8] = *(uint4*)l8;
      }
    } else {
      // B[k][n]: thread owns column n = sm, k-half sq; coalesced dword loads
      float v[16];
      const float* bp = Bw + (long)(k0 + sq * 16) * N + (n0 + sm);
#pragma unroll
      for (int j = 0; j < 16; j++) v[j] = bp[(long)j * N];
#pragma unroll
      for (int cc = 0; cc < 2; cc++) {
        int c = sq * 2 + cc;
        unsigned short h8[8], l8[8];
#pragma unroll
        for (int j = 0; j < 8; j++) {
          float x = v[cc * 8 + j];
          h8[j] = f2bf(x);
          l8[j] = f2bf(x - bf2f(h8[j]));
        }
        int cp = (c + (sm >> 1)) & 3;
        *(uint4*)&Bh[sm][cp * 8] = *(uint4*)h8;
        *(uint4*)&Bl[sm][cp * 8] = *(uint4*)l8;
      }
    }
    __syncthreads();

    // ---- fragment loads (b128, conflict-free via rotation) + MFMA
    bfrag a_h[4], a_l[4], b_h[4], b_l[4];
#pragma unroll
    for (int f = 0; f < 4; f++) {
      int ar = wm + f * 16 + fr;
      int ac = ((fg + (ar >> 1)) & 3) * 8;
      a_h[f] = *(const bfrag*)&Ah[ar][ac];
      a_l[f] = *(const bfrag*)&Al[ar][ac];
      int br = wn + f * 16 + fr;
      int bc = ((fg + (br >> 1)) & 3) * 8;
      b_h[f] = *(const bfrag*)&Bh[br][bc];
      b_l[f] = *(const bfrag*)&Bl[br][bc];
    }
#pragma unroll
    for (int fi = 0; fi < 4; fi++)
#pragma unroll
      for (int fj = 0; fj < 4; fj++) {
        acc[fi][fj] = __builtin_amdgcn_mfma_f32_16x16x32_bf16(a_h[fi], b_h[fj], acc[fi][fj], 0, 0, 0);
        acc[fi][fj] = __builtin_amdgcn_mfma_f32_16x16x32_bf16(a_h[fi], b_l[fj], acc[fi][fj], 0, 0, 0);
        acc[fi][fj] = __builtin_amdgcn_mfma_f32_16x16x32_bf16(a_l[fi], b_h[fj], acc[fi][fj], 0, 0, 0);
      }
    __syncthreads();
  }

  // ---- epilogue: C/D layout (verified): col = lane&15, row = (lane>>4)*4 + reg
#pragma unroll
  for (int fi = 0; fi < 4; fi++) {
    int rbase = m0 + wm + fi * 16 + fg * 4;
#pragma unroll
    for (int i = 0; i < 4; i++) {
      int mrow = rbase + i;
#pragma unroll
      for (int fj = 0; fj < 4; fj++) {
        int ncol = n0 + wn + fj * 16 + fr;
        float t = acc[fi][fj][i];
        if (bias)  t += bias[ncol];
        if (GELU_) t = gelu_f(t);
        if (resid) t += resid[(long)mrow * N + ncol];
        Cp[cbase + (long)mrow * N + ncol] = t;
      }
    }
  }
}

static inline void gemm_launch(hipStream_t st, bool bt, bool gelu,
    const float* A, const float* Bw, float* C, const float* bias, const float* resid,
    int M, int N, int Kd, long sA, long sB, long sC, long sBias, long sRes, int nz)
{
  dim3 g(N / 128, M / 128, nz), b(256, 1, 1);
  if (bt)
    gemm_mfma_k<true, false><<<g, b, 0, st>>>(A, Bw, C, bias, resid, M, N, Kd, sA, sB, sC, sBias, sRes);
  else if (gelu)
    gemm_mfma_k<false, true><<<g, b, 0, st>>>(A, Bw, C, bias, resid, M, N, Kd, sA, sB, sC, sBias, sRes);
  else
    gemm_mfma_k<false, false><<<g, b, 0, st>>>(A, Bw, C, bias, resid, M, N, Kd, sA, sB, sC, sBias, sRes);
}

extern "C" void kernel_launch(void* const* d_in, const int* in_sizes, int n_in,
                              void* d_out, int out_size, void* d_ws, size_t ws_size,
                              hipStream_t stream)
{
  (void)in_sizes; (void)n_in; (void)out_size; (void)ws_size;
  const int*   input_ids  = (const int*)  d_in[0];
  const float* tok_emb    = (const float*)d_in[1];
  const float* trunk_wq   = (const float*)d_in[2];
  const float* trunk_wk   = (const float*)d_in[3];
  const float* trunk_wv   = (const float*)d_in[4];
  const float* trunk_wo   = (const float*)d_in[5];
  const float* trunk_w1   = (const float*)d_in[6];
  const float* trunk_w2   = (const float*)d_in[7];
  const float* trunk_n1   = (const float*)d_in[8];
  const float* trunk_n2   = (const float*)d_in[9];
  const float* col_in_w   = (const float*)d_in[10];
  const float* col_in_b   = (const float*)d_in[11];
  const float* col_wq     = (const float*)d_in[12];
  const float* col_wk     = (const float*)d_in[13];
  const float* col_wv     = (const float*)d_in[14];
  const float* col_wo     = (const float*)d_in[15];
  const float* col_w1     = (const float*)d_in[16];
  const float* col_w2     = (const float*)d_in[17];
  const float* col_n1     = (const float*)d_in[18];
  const float* col_n2     = (const float*)d_in[19];
  const float* mrg_wq     = (const float*)d_in[20];
  const float* mrg_wk     = (const float*)d_in[21];
  const float* mrg_wv     = (const float*)d_in[22];
  const float* mrg_wo     = (const float*)d_in[23];
  const float* mrg_n      = (const float*)d_in[24];
  const float* out_proj   = (const float*)d_in[25];
  const float* final_norm = (const float*)d_in[26];

  // workspace layout (fp32): X,H,Q,K,V,CT,CS = 7 x 2M floats; FF aliases Q..CT (8M floats)
  const size_t M2 = (size_t)2 * 1024 * 1024;
  float* Xf  = (float*)d_ws;
  float* Hf  = Xf + M2;
  float* Qf  = Hf + M2;
  float* Kf  = Qf + M2;
  float* Vf  = Kf + M2;
  float* CTf = Vf + M2;
  float* CSf = CTf + M2;
  float* FFf = Qf;

  const int BT = B_ * T_;            // 2048
  const float scale = 0.125f;        // 64^-0.5

  embed_k<<<BT, 256, 0, stream>>>(input_ids, tok_emb, Xf);

  // ---------------- trunk ----------------
  for (int l = 0; l < LT_; l++) {
    const float* wq = trunk_wq + (size_t)l * D_ * D_;
    const float* wk = trunk_wk + (size_t)l * D_ * D_;
    const float* wv = trunk_wv + (size_t)l * D_ * D_;
    const float* wo = trunk_wo + (size_t)l * D_ * D_;
    const float* w1 = trunk_w1 + (size_t)l * D_ * DFF_;
    const float* w2 = trunk_w2 + (size_t)l * DFF_ * D_;
    const float* n1 = trunk_n1 + (size_t)l * D_;
    const float* n2 = trunk_n2 + (size_t)l * D_;

    rmsnorm_k<<<BT, 256, 0, stream>>>(Xf, Hf, n1, D_, 1, 0);
    gemm_launch(stream, false, false, Hf, wq, Qf, nullptr, nullptr, BT, D_, D_, 0,0,0,0,0, 1);
    gemm_launch(stream, false, false, Hf, wk, Kf, nullptr, nullptr, BT, D_, D_, 0,0,0,0,0, 1);
    gemm_launch(stream, false, false, Hf, wv, Vf, nullptr, nullptr, BT, D_, D_, 0,0,0,0,0, 1);
    {
      long total = (long)BT * HT_ * 32;
      rope_k<<<(int)(total / 256), 256, 0, stream>>>(Qf, total, T_, HT_);
      rope_k<<<(int)(total / 256), 256, 0, stream>>>(Kf, total, T_, HT_);
    }
    attn_k<<<dim3(T_, HT_, B_), 256, 0, stream>>>(Qf, Kf, Vf, CTf, T_, HT_, scale);
    gemm_launch(stream, false, false, CTf, wo, Xf, nullptr, Xf, BT, D_, D_, 0,0,0,0,0, 1);
    rmsnorm_k<<<BT, 256, 0, stream>>>(Xf, Hf, n2, D_, 1, 0);
    gemm_launch(stream, false, true, Hf, w1, FFf, nullptr, nullptr, BT, DFF_, D_, 0,0,0,0,0, 1);
    gemm_launch(stream, false, false, FFf, w2, Xf, nullptr, Xf, BT, D_, DFF_, 0,0,0,0,0, 1);
  }

  // ---------------- column input projection ----------------
  gemm_launch(stream, false, false, Xf, col_in_w, CSf, col_in_b, nullptr,
              BT, DC_, D_, 0, (long)D_ * DC_, (long)BT * DC_, DC_, 0, C_);

  // ---------------- column layers ----------------
  for (int l = 0; l < LC_; l++) {
    const float* cwq = col_wq + (size_t)l * DC_ * DC_;
    const float* cwk = col_wk + (size_t)l * DC_ * DC_;
    const float* cwv = col_wv + (size_t)l * DC_ * DC_;
    const float* cwo = col_wo + (size_t)l * DC_ * DC_;
    const float* cw1 = col_w1 + (size_t)l * DC_ * DFFC_;
    const float* cw2 = col_w2 + (size_t)l * DFFC_ * DC_;
    const long sW   = (long)LC_ * DC_ * DC_;
    const long sW1  = (long)LC_ * DC_ * DFFC_;
    const long sW2  = (long)LC_ * DFFC_ * DC_;
    const long sRow = (long)BT * DC_;

    rmsnorm_k<<<C_ * BT, 256, 0, stream>>>(CSf, Hf, col_n1 + (size_t)l * DC_, DC_, BT, (long)LC_ * DC_);
    gemm_launch(stream, false, false, Hf, cwq, Qf, nullptr, nullptr, BT, DC_, DC_, sRow, sW, sRow, 0, 0, C_);
    gemm_launch(stream, false, false, Hf, cwk, Kf, nullptr, nullptr, BT, DC_, DC_, sRow, sW, sRow, 0, 0, C_);
    gemm_launch(stream, false, false, Hf, cwv, Vf, nullptr, nullptr, BT, DC_, DC_, sRow, sW, sRow, 0, 0, C_);
    {
      long total = (long)C_ * BT * HC_ * 32;
      rope_k<<<(int)(total / 256), 256, 0, stream>>>(Qf, total, T_, HC_);
      rope_k<<<(int)(total / 256), 256, 0, stream>>>(Kf, total, T_, HC_);
    }
    attn_k<<<dim3(T_, HC_, C_ * B_), 256, 0, stream>>>(Qf, Kf, Vf, CTf, T_, HC_, scale);
    gemm_launch(stream, false, false, CTf, cwo, CSf, nullptr, CSf, BT, DC_, DC_, sRow, sW, sRow, 0, sRow, C_);
    rmsnorm_k<<<C_ * BT, 256, 0, stream>>>(CSf, Hf, col_n2 + (size_t)l * DC_, DC_, BT, (long)LC_ * DC_);
    gemm_launch(stream, false, true, Hf, cw1, FFf, nullptr, nullptr, BT, DFFC_, DC_,
                sRow, sW1, (long)BT * DFFC_, 0, 0, C_);
    gemm_launch(stream, false, false, FFf, cw2, CSf, nullptr, CSf, BT, DC_, DFFC_,
                (long)BT * DFFC_, sW2, sRow, 0, sRow, C_);

    if ((l + 1) % 2 == 0) {
      int mi = (l + 1) / 2 - 1;
      const float* mwq = mrg_wq + (size_t)mi * DC_ * DC_;
      const float* mwk = mrg_wk + (size_t)mi * DC_ * DC_;
      const float* mwv = mrg_wv + (size_t)mi * DC_ * DC_;
      const float* mwo = mrg_wo + (size_t)mi * DC_ * DC_;
      rmsnorm_k<<<C_ * BT, 256, 0, stream>>>(CSf, Hf, mrg_n + (size_t)mi * DC_, DC_, 1, 0);
      gemm_launch(stream, false, false, Hf, mwq, Qf, nullptr, nullptr, C_ * BT, DC_, DC_, 0,0,0,0,0, 1);
      gemm_launch(stream, false, false, Hf, mwk, Kf, nullptr, nullptr, C_ * BT, DC_, DC_, 0,0,0,0,0, 1);
      gemm_launch(stream, false, false, Hf, mwv, Vf, nullptr, nullptr, C_ * BT, DC_, DC_, 0,0,0,0,0, 1);
      merge_attn_k<<<BT * HC_, 64, 0, stream>>>(Qf, Kf, Vf, CTf, scale);
      gemm_launch(stream, false, false, CTf, mwo, CSf, nullptr, CSf, C_ * BT, DC_, DC_, 0,0,0,0,0, 1);
    }
  }

  // ---------------- head ----------------
  transpose_cs_k<<<(C_ * BT * DC_) / 256, 256, 0, stream>>>(CSf, Xf);
  gemm_launch(stream, false, false, Xf, out_proj, CTf, nullptr, nullptr, BT, D_, D_, 0,0,0,0,0, 1);
  rmsnorm_k<<<BT, 256, 0, stream>>>(CTf, Xf, final_norm, D_, 1, 0);
  // logits = normed @ tok_emb^T  (fp32 out)
  gemm_launch(stream, true, false, Xf, tok_emb, (float*)d_out, nullptr, nullptr, BT, VSZ_, D_, 0,0,0,0,0, 1);
}